// Round 2
// baseline (327.411 us; speedup 1.0000x reference)
//
#include <hip/hip_runtime.h>

typedef __bf16 bf16_t;
typedef __bf16 bf16x8 __attribute__((ext_vector_type(8)));
typedef float f32x4 __attribute__((ext_vector_type(4)));
typedef unsigned short us4 __attribute__((ext_vector_type(4)));
typedef unsigned short us8 __attribute__((ext_vector_type(8)));

// ---------------- fused foveation ----------------
// All three scales' patches are nested: region = 128x128 at (st-65, st-65);
// scale2 = 64x64 at +32, scale1 = 32x32 at +48. Stage region once in LDS.
__global__ __launch_bounds__(256) void foveate2(const float* __restrict__ x,
                                                const float* __restrict__ l,
                                                bf16_t* __restrict__ g)
{
  __shared__ float R[128 * 128];
  const int b = blockIdx.x, ch = blockIdx.y;
  const float l0 = l[2 * b], l1 = l[2 * b + 1];
  // reference-exact: trunc(0.5f*((l+1.0f)*224.0f)), values >= 0
  const int st0 = (int)(0.5f * ((l0 + 1.0f) * 224.0f));  // col
  const int st1 = (int)(0.5f * ((l1 + 1.0f) * 224.0f));  // row
  const int r0 = st1 - 65, c0 = st0 - 65;
  const float* xc = x + ((size_t)b * 3 + ch) * 50176;

  // stage 128x128 (zero-padded OOB), coalesced: 2 rows per 256-thread step
  for (int it = 0; it < 64; ++it) {
    const int p = it * 256 + threadIdx.x;
    const int r = p >> 7, c = p & 127;
    const int gr = r0 + r, gc = c0 + c;
    float v = 0.0f;
    if ((unsigned)gr < 224u && (unsigned)gc < 224u) v = xc[gr * 224 + gc];
    R[p] = v;
  }
  __syncthreads();

  bf16_t* gb = g + (size_t)b * 9216 + ch * 1024;
  // scale 1 (k=0): copy central 32x32 at offset 48
  for (int it = 0; it < 4; ++it) {
    const int q = it * 256 + threadIdx.x;
    const int gy = q >> 5, gx = q & 31;
    gb[q] = (bf16_t)R[(48 + gy) * 128 + 48 + gx];
  }
  // scale 2 (k=1): 2x2 avg of central 64x64 at offset 32
  for (int it = 0; it < 4; ++it) {
    const int q = it * 256 + threadIdx.x;
    const int gy = q >> 5, gx = q & 31;
    const int base = (32 + 2 * gy) * 128 + 32 + 2 * gx;
    const float s = R[base] + R[base + 1] + R[base + 128] + R[base + 129];
    gb[3072 + q] = (bf16_t)(s * 0.25f);
  }
  // scale 3 (k=2): 4x4 avg of full region (float4 rows, 16B aligned)
  for (int it = 0; it < 4; ++it) {
    const int q = it * 256 + threadIdx.x;
    const int gy = q >> 5, gx = q & 31;
    float s = 0.0f;
#pragma unroll
    for (int dy = 0; dy < 4; ++dy) {
      const f32x4 v = *(const f32x4*)&R[(4 * gy + dy) * 128 + 4 * gx];
      s += v[0] + v[1] + v[2] + v[3];
    }
    gb[6144 + q] = (bf16_t)(s * 0.0625f);
  }
}

// ---------------- LDS-free split-K bf16 MFMA GEMM ----------------
// A: bf16 [M x KFULL] k-contiguous (M = WAVES*32, gridDim.x = 1).
// B: fp32 [KFULL x NDIM] row-major; rows k < KB1 from Bp0 else Bp1.
// Fragments loaded straight from global: A one us8/frag; B 8 strided dwords
// + in-register bf16 pack. No LDS, no barriers in the K loop.
template<int WAVES, int BN, int KCHUNK, int NDIM, int KFULL, int KB1>
__global__ __launch_bounds__(WAVES * 64) void gemm_direct(const bf16_t* __restrict__ A,
                                                          const float* __restrict__ Bp0,
                                                          const float* __restrict__ Bp1,
                                                          float* __restrict__ part)
{
  constexpr int SM = 2;          // wave tile: 32 (m) x BN (n)
  constexpr int SN = BN / 16;
  constexpr int M = WAVES * 32;
  const int t = threadIdx.x, w = t >> 6, lane = t & 63;
  const int lr = lane & 15, kg = lane >> 4;
  const int bn0 = blockIdx.y * BN;
  const int ks0 = blockIdx.z * KCHUNK;
  const int m0 = w * 32;

  f32x4 acc[SM][SN] = {};
#pragma unroll 2
  for (int k0 = 0; k0 < KCHUNK; k0 += 32) {
    const int kbase = ks0 + k0;
    const float* brow = (kbase < KB1) ? (Bp0 + (size_t)kbase * NDIM)
                                      : (Bp1 + (size_t)(kbase - KB1) * NDIM);
    bf16x8 af[SM];
#pragma unroll
    for (int sm = 0; sm < SM; ++sm)
      af[sm] = __builtin_bit_cast(bf16x8,
          *(const us8*)(A + (size_t)(m0 + sm * 16 + lr) * KFULL + kbase + kg * 8));
    bf16x8 bfr[SN];
#pragma unroll
    for (int sn = 0; sn < SN; ++sn) {
      const float* bp = brow + (size_t)(kg * 8) * NDIM + bn0 + sn * 16 + lr;
#pragma unroll
      for (int j = 0; j < 8; ++j) bfr[sn][j] = (bf16_t)bp[(size_t)j * NDIM];
    }
#pragma unroll
    for (int sm = 0; sm < SM; ++sm)
#pragma unroll
      for (int sn = 0; sn < SN; ++sn)
        acc[sm][sn] = __builtin_amdgcn_mfma_f32_16x16x32_bf16(af[sm], bfr[sn], acc[sm][sn], 0, 0, 0);
  }
  // fp32 partials, C/D layout: col = lr, row = kg*4 + r
  float* outp = part + (size_t)blockIdx.z * ((size_t)M * NDIM);
#pragma unroll
  for (int sm = 0; sm < SM; ++sm)
#pragma unroll
    for (int sn = 0; sn < SN; ++sn)
#pragma unroll
      for (int r = 0; r < 4; ++r) {
        const int gm = m0 + sm * 16 + kg * 4 + r;
        const int gn = bn0 + sn * 16 + lr;
        outp[(size_t)gm * NDIM + gn] = acc[sm][sn][r];
      }
}

// ---------------- reduce GEMM1 partials (16) + bias + relu -> bf16; l_out path ----------------
__global__ __launch_bounds__(256) void fuse_mid(const float* __restrict__ part1,
                                                const float* __restrict__ b1,
                                                const float* __restrict__ lprev,
                                                const float* __restrict__ W2,
                                                const float* __restrict__ b2,
                                                bf16_t* __restrict__ A2)
{
  const int e = (blockIdx.x * 256 + threadIdx.x) * 4;  // 4 elems/thread; block = half row
  const int row = e >> 11, col = e & 2047;
  f32x4 s;
  if (col < 1024) {
    s = *(const f32x4*)(b1 + col);
#pragma unroll
    for (int z = 0; z < 16; ++z)
      s += *(const f32x4*)(part1 + (size_t)z * 262144 + row * 1024 + col);
  } else {
    const int n = col - 1024;
    const f32x4 w0 = *(const f32x4*)(W2 + n);
    const f32x4 w1 = *(const f32x4*)(W2 + 1024 + n);
    s = *(const f32x4*)(b2 + n) + lprev[2 * row] * w0 + lprev[2 * row + 1] * w1;
  }
  us4 o;
#pragma unroll
  for (int j = 0; j < 4; ++j)
    o[j] = __builtin_bit_cast(unsigned short, (bf16_t)fmaxf(s[j], 0.0f));
  *(us4*)(A2 + e) = o;
}

// ---------------- reduce GEMM2 partials (8) + (b3+b4) + relu -> fp32 out ----------------
__global__ __launch_bounds__(256) void epilogue2(const float* __restrict__ part2,
                                                 const float* __restrict__ b3,
                                                 const float* __restrict__ b4,
                                                 float* __restrict__ out)
{
  const int e = (blockIdx.x * 256 + threadIdx.x) * 4;
  const int col = e & 2047;
  f32x4 s = *(const f32x4*)(b3 + col) + *(const f32x4*)(b4 + col);
#pragma unroll
  for (int z = 0; z < 8; ++z)
    s += *(const f32x4*)(part2 + (size_t)z * 524288 + e);
  f32x4 o;
#pragma unroll
  for (int j = 0; j < 4; ++j) o[j] = fmaxf(s[j], 0.0f);
  *(f32x4*)(out + e) = o;
}

extern "C" void kernel_launch(void* const* d_in, const int* in_sizes, int n_in,
                              void* d_out, int out_size, void* d_ws, size_t ws_size,
                              hipStream_t stream)
{
  const float* x     = (const float*)d_in[0];
  const float* lprev = (const float*)d_in[1];
  const float* W1    = (const float*)d_in[2];   // (9216, 1024)
  const float* b1    = (const float*)d_in[3];
  const float* W2    = (const float*)d_in[4];   // (2, 1024)
  const float* b2    = (const float*)d_in[5];
  const float* W3    = (const float*)d_in[6];   // (1024, 2048)
  const float* b3    = (const float*)d_in[7];
  const float* W4    = (const float*)d_in[8];   // (1024, 2048)
  const float* b4    = (const float*)d_in[9];
  float* out = (float*)d_out;

  // workspace layout, total ~39.3 MB (ws is ~588 MB per harness poison fill)
  char* ws = (char*)d_ws;
  bf16_t* glimpse = (bf16_t*)ws;                 // 256*9216*2    = 4,718,592 B
  bf16_t* A2      = (bf16_t*)(ws + 4718592);     // 256*2048*2    = 1,048,576 B
  float*  part1   = (float*)(ws + 5767168);      // 16*256*1024*4 = 16,777,216 B
  float*  part2   = (float*)(ws + 22544384);     // 8*256*2048*4  = 16,777,216 B

  foveate2<<<dim3(256, 3), 256, 0, stream>>>(x, lprev, glimpse);
  // GEMM1: M=256,N=1024,K=9216; splitK=16 (chunk 576); 16 n-tiles -> 256 blocks x 512 thr
  gemm_direct<8, 64, 576, 1024, 9216, 9216>
      <<<dim3(1, 16, 16), 512, 0, stream>>>(glimpse, W1, W1, part1);
  fuse_mid<<<512, 256, 0, stream>>>(part1, b1, lprev, W2, b2, A2);
  // GEMM2: M=256,N=2048,K=2048 ([g_out|l_out]@[W3;W4]); splitK=8 (chunk 256); 256 blocks
  gemm_direct<8, 64, 256, 2048, 2048, 1024>
      <<<dim3(1, 32, 8), 512, 0, stream>>>(A2, W3, W4, part2);
  epilogue2<<<512, 256, 0, stream>>>(part2, b3, b4, out);
}